// Round 1
// baseline (15694.089 us; speedup 1.0000x reference)
//
#include <hip/hip_runtime.h>
#include <cstddef>

#define LEAK  0.99f
#define THRS  1.0f
#define BNEPS 1e-4f

static constexpr int TT   = 8;
static constexpr int BB   = 4;
static constexpr int NCLS = 21;
static constexpr int COB  = 8;   // output channels per thread

__global__ void zero_f32(float* __restrict__ p, int n) {
  int i = blockIdx.x * blockDim.x + threadIdx.x;
  int stride = gridDim.x * blockDim.x;
  for (; i < n; i += stride) p[i] = 0.0f;
}

__global__ void scale_f32(float* __restrict__ p, int n, float s) {
  int i = blockIdx.x * blockDim.x + threadIdx.x;
  if (i < n) p[i] *= s;
}

// Poisson generator: s = (u <= |x|) ? sign(x) : 0
__global__ void spike_gen(const float* __restrict__ x, const float* __restrict__ u,
                          float* __restrict__ s, int n) {
  int i = blockIdx.x * blockDim.x + threadIdx.x;
  if (i >= n) return;
  float xv = x[i];
  float ax = fabsf(xv);
  float sg = (xv > 0.0f) ? 1.0f : ((xv < 0.0f) ? -1.0f : 0.0f);
  s[i] = (u[i] <= ax) ? sg : 0.0f;
}

// Fused: conv3x3 (pad == dil) -> BN (gamma,mu,var; no bias) -> LIF
//   mem' = LEAK*mem + bn_out ; spike = mem' > THR ; out = spike ; mem = mem' - spike
// Thread = one spatial pixel, COB consecutive output channels.
// Block = 256 threads = 16x16 spatial tile. grid = (tiles, Co/COB, B)
__global__ void lif_conv(const float* __restrict__ in, const float* __restrict__ Wt,
                         const float* __restrict__ bnt,   // [3][Co] for this timestep
                         float* __restrict__ mem, float* __restrict__ out,
                         int Ci, int Co, int H, int W, int dil) {
  const int b   = blockIdx.z;
  const int co0 = blockIdx.y * COB;
  const int tpr = W >> 4;
  const int x = ((blockIdx.x % tpr) << 4) + (threadIdx.x & 15);
  const int y = ((blockIdx.x / tpr) << 4) + (threadIdx.x >> 4);

  const int ym = y - dil, yp = y + dil;
  const int xm = x - dil, xp = x + dil;
  const bool vy0 = (ym >= 0), vy2 = (yp < H);
  const bool vx0 = (xm >= 0), vx2 = (xp < W);

  const int HW = H * W;
  const float* __restrict__ ib = in + (size_t)b * Ci * HW;

  float acc[COB];
#pragma unroll
  for (int j = 0; j < COB; ++j) acc[j] = 0.0f;

  for (int ci = 0; ci < Ci; ++ci) {
    const float* __restrict__ ip = ib + (size_t)ci * HW;
    float v[9];
    v[0] = (vy0 && vx0) ? ip[ym * W + xm] : 0.0f;
    v[1] = (vy0)        ? ip[ym * W + x ] : 0.0f;
    v[2] = (vy0 && vx2) ? ip[ym * W + xp] : 0.0f;
    v[3] = (vx0)        ? ip[y  * W + xm] : 0.0f;
    v[4] =                ip[y  * W + x ];
    v[5] = (vx2)        ? ip[y  * W + xp] : 0.0f;
    v[6] = (vy2 && vx0) ? ip[yp * W + xm] : 0.0f;
    v[7] = (vy2)        ? ip[yp * W + x ] : 0.0f;
    v[8] = (vy2 && vx2) ? ip[yp * W + xp] : 0.0f;

    const float* __restrict__ wp = Wt + ((size_t)co0 * Ci + ci) * 9;  // wave-uniform
#pragma unroll
    for (int j = 0; j < COB; ++j) {
      const float* __restrict__ w = wp + (size_t)j * Ci * 9;
#pragma unroll
      for (int k = 0; k < 9; ++k) acc[j] = fmaf(v[k], w[k], acc[j]);
    }
  }

  // BN + LIF epilogue
  const size_t pbase = ((size_t)b * Co + co0) * HW + (size_t)y * W + x;
#pragma unroll
  for (int j = 0; j < COB; ++j) {
    const int c = co0 + j;
    const float g   = bnt[c];
    const float mu  = bnt[Co + c];
    const float var = bnt[2 * Co + c];
    const float inv = g / sqrtf(var + BNEPS);
    const float bno = (acc[j] - mu) * inv;
    const size_t idx = pbase + (size_t)j * HW;
    float m = LEAK * mem[idx] + bno;
    float sp = (m > THRS) ? 1.0f : 0.0f;
    out[idx] = sp;
    mem[idx] = m - sp;   // THR == 1
  }
}

// AvgPool2d(k=3, s=2, p=1), count_include_pad=True (always /9)
__global__ void avgpool_k(const float* __restrict__ in, float* __restrict__ out,
                          int C, int H, int W) {
  const int Ho = H >> 1, Wo = W >> 1;
  const int n = BB * C * Ho * Wo;
  int i = blockIdx.x * blockDim.x + threadIdx.x;
  if (i >= n) return;
  int xo = i % Wo; int t = i / Wo;
  int yo = t % Ho; t /= Ho;
  int c = t % C;  int b = t / C;
  const float* __restrict__ ip = in + ((size_t)b * C + c) * H * W;
  const int y0 = 2 * yo - 1, x0 = 2 * xo - 1;
  float s = 0.0f;
#pragma unroll
  for (int dy = 0; dy < 3; ++dy) {
    int iy = y0 + dy;
    if (iy < 0 || iy >= H) continue;
#pragma unroll
    for (int dx = 0; dx < 3; ++dx) {
      int ix = x0 + dx;
      if (ix < 0 || ix >= W) continue;
      s += ip[iy * W + ix];
    }
  }
  out[i] = s * (1.0f / 9.0f);
}

// 1x1 conv 1024 -> 21 @32x32, accumulate into out
__global__ void out_conv(const float* __restrict__ in, const float* __restrict__ W8,
                         float* __restrict__ out) {
  const int pix = blockIdx.x * 256 + threadIdx.x;   // 0..1023
  const int cls = blockIdx.y;
  const int b   = blockIdx.z;
  const float* __restrict__ ip = in + ((size_t)b << 20) + pix;  // b*1024*1024
  const float* __restrict__ wp = W8 + (size_t)cls * 1024;
  float a = 0.0f;
  for (int ci = 0; ci < 1024; ++ci) a = fmaf(ip[(size_t)ci << 10], wp[ci], a);
  out[(((size_t)b * NCLS + cls) << 10) + pix] += a;
}

extern "C" void kernel_launch(void* const* d_in, const int* in_sizes, int n_in,
                              void* d_out, int out_size, void* d_ws, size_t ws_size,
                              hipStream_t stream) {
  const float* x = (const float*)d_in[0];
  const float* u = (const float*)d_in[1];
  const float* Wc[9];
  for (int i = 0; i < 9; ++i) Wc[i] = (const float*)d_in[2 + i];
  const float* bn[8];
  for (int i = 0; i < 8; ++i) bn[i] = (const float*)d_in[11 + i];

  float* ws = (float*)d_ws;
  size_t off = 0;
  float* m0 = ws + off; off += (size_t)BB * 64 * 128 * 128;
  float* m1 = ws + off; off += (size_t)BB * 64 * 128 * 128;
  float* m2 = ws + off; off += (size_t)BB * 128 * 64 * 64;
  float* m3 = ws + off; off += (size_t)BB * 128 * 64 * 64;
  float* m4 = ws + off; off += (size_t)BB * 256 * 32 * 32;
  float* m5 = ws + off; off += (size_t)BB * 256 * 32 * 32;
  float* m6 = ws + off; off += (size_t)BB * 256 * 32 * 32;
  float* m7 = ws + off; off += (size_t)BB * 1024 * 32 * 32;
  const size_t memtot = off;
  float* bufA = ws + off; off += (size_t)BB * 64 * 128 * 128;
  float* bufB = ws + off; off += (size_t)BB * 64 * 128 * 128;

  // zero membrane states + output accumulator (must be re-done every call)
  zero_f32<<<2048, 256, 0, stream>>>(ws, (int)memtot);
  zero_f32<<<(BB * NCLS * 1024 + 255) / 256, 256, 0, stream>>>((float*)d_out, BB * NCLS * 1024);

  const int nspk = BB * 3 * 128 * 128;
  for (int t = 0; t < TT; ++t) {
    spike_gen<<<(nspk + 255) / 256, 256, 0, stream>>>(x, u + (size_t)t * nspk, bufA, nspk);
    // L0: 3->64 @128
    lif_conv<<<dim3(64, 64 / COB, BB), 256, 0, stream>>>(bufA, Wc[0], bn[0] + (size_t)t * 3 * 64,  m0, bufB, 3,   64,  128, 128, 1);
    // L1: 64->64 @128
    lif_conv<<<dim3(64, 64 / COB, BB), 256, 0, stream>>>(bufB, Wc[1], bn[1] + (size_t)t * 3 * 64,  m1, bufA, 64,  64,  128, 128, 1);
    avgpool_k<<<(BB * 64 * 64 * 64 + 255) / 256, 256, 0, stream>>>(bufA, bufB, 64, 128, 128);
    // L2: 64->128 @64
    lif_conv<<<dim3(16, 128 / COB, BB), 256, 0, stream>>>(bufB, Wc[2], bn[2] + (size_t)t * 3 * 128, m2, bufA, 64,  128, 64, 64, 1);
    // L3: 128->128 @64
    lif_conv<<<dim3(16, 128 / COB, BB), 256, 0, stream>>>(bufA, Wc[3], bn[3] + (size_t)t * 3 * 128, m3, bufB, 128, 128, 64, 64, 1);
    avgpool_k<<<(BB * 128 * 32 * 32 + 255) / 256, 256, 0, stream>>>(bufB, bufA, 128, 64, 64);
    // L4: 128->256 @32
    lif_conv<<<dim3(4, 256 / COB, BB), 256, 0, stream>>>(bufA, Wc[4], bn[4] + (size_t)t * 3 * 256, m4, bufB, 128, 256, 32, 32, 1);
    // L5: 256->256 @32 dil2
    lif_conv<<<dim3(4, 256 / COB, BB), 256, 0, stream>>>(bufB, Wc[5], bn[5] + (size_t)t * 3 * 256, m5, bufA, 256, 256, 32, 32, 2);
    // L6: 256->256 @32 dil2
    lif_conv<<<dim3(4, 256 / COB, BB), 256, 0, stream>>>(bufA, Wc[6], bn[6] + (size_t)t * 3 * 256, m6, bufB, 256, 256, 32, 32, 2);
    // L7: 256->1024 @32 dil12
    lif_conv<<<dim3(4, 1024 / COB, BB), 256, 0, stream>>>(bufB, Wc[7], bn[7] + (size_t)t * 3 * 1024, m7, bufA, 256, 1024, 32, 32, 12);
    // output layer: macc += conv1x1
    out_conv<<<dim3(4, NCLS, BB), 256, 0, stream>>>(bufA, Wc[8], (float*)d_out);
  }
  scale_f32<<<(BB * NCLS * 1024 + 255) / 256, 256, 0, stream>>>((float*)d_out, BB * NCLS * 1024, 1.0f / TT);
}

// Round 2
// 4861.726 us; speedup vs baseline: 3.2281x; 3.2281x over previous
//
#include <hip/hip_runtime.h>
#include <hip/hip_bf16.h>
#include <cstddef>

#define LEAK  0.99f
#define THRS  1.0f
#define BNEPS 1e-4f

static constexpr int TT   = 8;
static constexpr int BB   = 4;
static constexpr int NCLS = 21;

typedef __attribute__((ext_vector_type(8))) short short8v;   // 8 bf16 = 4 VGPR (MFMA A/B frag)
typedef __attribute__((ext_vector_type(4))) float f32x4;     // MFMA C/D frag

__global__ void zero_f32(float* __restrict__ p, int n) {
  int i = blockIdx.x * blockDim.x + threadIdx.x;
  int stride = gridDim.x * blockDim.x;
  for (; i < n; i += stride) p[i] = 0.0f;
}

__global__ void scale_f32(float* __restrict__ p, int n, float s) {
  int i = blockIdx.x * blockDim.x + threadIdx.x;
  if (i < n) p[i] *= s;
}

// Split f32 weights (scaled) into hi+lo bf16, reordered to k = tap*Cip + ci.
// Wsrc: [Co][Ci][9] f32.  whi/wlo: [Co][9*Cip] bf16, zero-padded ci in [Ci,Cip).
__global__ void wsplit(const float* __restrict__ Wsrc,
                       __hip_bfloat16* __restrict__ whi, __hip_bfloat16* __restrict__ wlo,
                       int Co, int Ci, int Cip, float scale) {
  const int Kpad = 9 * Cip;
  const int n = Co * Kpad;
  int i = blockIdx.x * 256 + threadIdx.x;
  if (i >= n) return;
  int co = i / Kpad, k = i - co * Kpad;
  int tap = k / Cip, ci = k - tap * Cip;
  float w = 0.0f;
  if (ci < Ci) w = Wsrc[((size_t)co * Ci + ci) * 9 + tap] * scale;
  __hip_bfloat16 h = __float2bfloat16(w);
  float r = w - __bfloat162float(h);
  whi[i] = h;
  wlo[i] = __float2bfloat16(r);
}

// Poisson generator, writes channel-last [B][HW][32] (ch 3..31 pre-zeroed once per call)
__global__ void spike_gen(const float* __restrict__ x, const float* __restrict__ u,
                          __hip_bfloat16* __restrict__ spk) {
  const int HW = 128 * 128;
  int i = blockIdx.x * 256 + threadIdx.x;  // b*HW + hw
  if (i >= BB * HW) return;
  int b = i / HW, hw = i - b * HW;
#pragma unroll
  for (int c = 0; c < 3; ++c) {
    float xv = x[((size_t)b * 3 + c) * HW + hw];
    float uv = u[((size_t)b * 3 + c) * HW + hw];
    float ax = fabsf(xv);
    float sg = (xv > 0.0f) ? 1.0f : ((xv < 0.0f) ? -1.0f : 0.0f);
    float s  = (uv <= ax) ? sg : 0.0f;
    spk[(size_t)i * 32 + c] = __float2bfloat16(s);
  }
}

// Implicit-GEMM conv3x3(pad==dil) + BN + LIF, MFMA 16x16x32 bf16, hi+lo weight split.
// actin : [B][H][W][Cip] bf16 (channel-last)     whi/wlo: [Co][9*Cip] bf16
// mem   : [B][H][W][Co] f32                      actout : [B][H][W][Co] bf16 (spikes)
// GEMM: D[pixel][co] ; A-frag = activations (m=pixel), B-frag = weights (n=co).
// grid = (P/64, Co/64), block = 256 (4 waves; wave tile 32px x 32co).
__global__ __launch_bounds__(256) void gemm_lif(
    const __hip_bfloat16* __restrict__ actin,
    const __hip_bfloat16* __restrict__ whi, const __hip_bfloat16* __restrict__ wlo,
    const float* __restrict__ bnt,        // [3][Co] for this timestep
    float* __restrict__ mem, __hip_bfloat16* __restrict__ actout,
    int Cip, int Co, int H, int W, int dil) {
  const int HW   = H * W;
  const int Kpad = 9 * Cip;
  const int lane = threadIdx.x & 63;
  const int wid  = threadIdx.x >> 6;
  const int wm = wid & 1, wn = wid >> 1;
  const int l15 = lane & 15, g = lane >> 4;
  const int p0  = blockIdx.x * 64 + wm * 32;
  const int cob = blockIdx.y * 64 + wn * 32;

  // pixel decompose per 16-px sub-block (16 consecutive px stay in one image row: W%16==0)
  int b_[2], y_[2], x0_[2];
#pragma unroll
  for (int bi = 0; bi < 2; ++bi) {
    int pb = p0 + bi * 16;
    int b = pb / HW; int rem = pb - b * HW;
    int y = rem / W; int x0 = rem - y * W;
    b_[bi] = b; y_[bi] = y; x0_[bi] = x0;
  }

  f32x4 acc[2][2] = {};

  const __hip_bfloat16* wrowh[2];
  const __hip_bfloat16* wrowl[2];
#pragma unroll
  for (int bj = 0; bj < 2; ++bj) {
    int co = cob + bj * 16 + l15;
    wrowh[bj] = whi + (size_t)co * Kpad + 8 * g;
    wrowl[bj] = wlo + (size_t)co * Kpad + 8 * g;
  }

  for (int tap = 0; tap < 9; ++tap) {
    const int dy = (tap / 3 - 1) * dil, dx = (tap % 3 - 1) * dil;
    const __hip_bfloat16* abase[2];
    bool av[2];
#pragma unroll
    for (int bi = 0; bi < 2; ++bi) {
      int sy = y_[bi] + dy;
      int sx = x0_[bi] + dx + l15;
      bool v = (sy >= 0) & (sy < H) & (sx >= 0) & (sx < W);
      av[bi] = v;
      int poff = v ? (b_[bi] * HW + sy * W + sx) : 0;
      abase[bi] = actin + (size_t)poff * Cip + 8 * g;
    }
    const int kk = tap * Cip;
    for (int c0 = 0; c0 < Cip; c0 += 32) {
      short8v a[2];
      const short8v zz = {};
#pragma unroll
      for (int bi = 0; bi < 2; ++bi)
        a[bi] = av[bi] ? *(const short8v*)(abase[bi] + c0) : zz;
#pragma unroll
      for (int bj = 0; bj < 2; ++bj) {
        short8v bh = *(const short8v*)(wrowh[bj] + kk + c0);
        short8v bl = *(const short8v*)(wrowl[bj] + kk + c0);
#pragma unroll
        for (int bi = 0; bi < 2; ++bi) {
          acc[bi][bj] = __builtin_amdgcn_mfma_f32_16x16x32_bf16(a[bi], bh, acc[bi][bj], 0, 0, 0);
          acc[bi][bj] = __builtin_amdgcn_mfma_f32_16x16x32_bf16(a[bi], bl, acc[bi][bj], 0, 0, 0);
        }
      }
    }
  }

  // epilogue: BN + LIF.  D layout: co = cob + bj*16 + (lane&15), pixel = p0 + bi*16 + 4*(lane>>4) + r
#pragma unroll
  for (int bj = 0; bj < 2; ++bj) {
    int c = cob + bj * 16 + l15;
    float ga = bnt[c], mu = bnt[Co + c], va = bnt[2 * Co + c];
    float sc = ga / sqrtf(va + BNEPS);
#pragma unroll
    for (int bi = 0; bi < 2; ++bi) {
      int pixbase = p0 + bi * 16 + 4 * g;
#pragma unroll
      for (int r = 0; r < 4; ++r) {
        size_t idx = (size_t)(pixbase + r) * Co + c;
        float bno = (acc[bi][bj][r] - mu) * sc;
        float m = LEAK * mem[idx] + bno;
        float s = (m > THRS) ? 1.0f : 0.0f;
        actout[idx] = __float2bfloat16(s);
        mem[idx] = m - s;
      }
    }
  }
}

// AvgPool(3,2,1) but storing SUM (exact integers in bf16); /9 folded into next layer weights.
// channel-last [B][H][W][C] -> [B][H/2][W/2][C]
__global__ void avgpool_sum(const __hip_bfloat16* __restrict__ in, __hip_bfloat16* __restrict__ out,
                            int C, int H, int W) {
  const int Ho = H >> 1, Wo = W >> 1;
  const int n = BB * Ho * Wo * C;
  int i = blockIdx.x * 256 + threadIdx.x;
  if (i >= n) return;
  int c = i % C; int t = i / C;
  int xo = t % Wo; t /= Wo;
  int yo = t % Ho; int b = t / Ho;
  const int y0 = 2 * yo - 1, x0 = 2 * xo - 1;
  float s = 0.0f;
#pragma unroll
  for (int dy = 0; dy < 3; ++dy) {
    int iy = y0 + dy;
    if (iy < 0 || iy >= H) continue;
#pragma unroll
    for (int dx = 0; dx < 3; ++dx) {
      int ix = x0 + dx;
      if (ix < 0 || ix >= W) continue;
      s += __bfloat162float(in[(((size_t)b * H + iy) * W + ix) * C + c]);
    }
  }
  out[i] = __float2bfloat16(s);
}

// 1x1 conv 1024->21 @32x32, f32, accumulate into d_out. One wave per (b,pix).
__global__ void out_conv(const __hip_bfloat16* __restrict__ act,  // [B][1024px][1024ch]
                         const float* __restrict__ W8, float* __restrict__ out) {
  int gw = (blockIdx.x * 256 + threadIdx.x) >> 6;  // b*1024 + pix
  int lane = threadIdx.x & 63;
  int b = gw >> 10, pix = gw & 1023;
  const __hip_bfloat16* ap = act + ((size_t)gw << 10);
  float acc[NCLS];
#pragma unroll
  for (int c = 0; c < NCLS; ++c) acc[c] = 0.0f;
  for (int j = 0; j < 16; ++j) {
    int ci = j * 64 + lane;
    float av = __bfloat162float(ap[ci]);
#pragma unroll
    for (int c = 0; c < NCLS; ++c) acc[c] = fmaf(av, W8[c * 1024 + ci], acc[c]);
  }
#pragma unroll
  for (int c = 0; c < NCLS; ++c) {
    float v = acc[c];
    for (int off = 32; off; off >>= 1) v += __shfl_xor(v, off, 64);
    if (lane == 0) out[((size_t)b * NCLS + c) * 1024 + pix] += v;
  }
}

extern "C" void kernel_launch(void* const* d_in, const int* in_sizes, int n_in,
                              void* d_out, int out_size, void* d_ws, size_t ws_size,
                              hipStream_t stream) {
  const float* x = (const float*)d_in[0];
  const float* u = (const float*)d_in[1];
  const float* Wc[9];
  for (int i = 0; i < 9; ++i) Wc[i] = (const float*)d_in[2 + i];
  const float* bn[8];
  for (int i = 0; i < 8; ++i) bn[i] = (const float*)d_in[11 + i];

  // layer geometry
  const int Ci_[8]  = {3, 64, 64, 128, 128, 256, 256, 256};
  const int Cip_[8] = {32, 64, 64, 128, 128, 256, 256, 256};
  const int Co_[8]  = {64, 64, 128, 128, 256, 256, 256, 1024};
  const int Hh_[8]  = {128, 128, 64, 64, 32, 32, 32, 32};
  const int dil_[8] = {1, 1, 1, 1, 1, 2, 2, 12};
  const float wsc_[8] = {1.f, 1.f, 1.f / 9.f, 1.f, 1.f / 9.f, 1.f, 1.f, 1.f};

  float* ws = (float*)d_ws;
  size_t off = 0;
  float* memp[8];
  for (int i = 0; i < 8; ++i) {
    memp[i] = ws + off;
    off += (size_t)BB * Hh_[i] * Hh_[i] * Co_[i];
  }
  __hip_bfloat16* spk = (__hip_bfloat16*)(ws + off);
  off += (size_t)BB * 16384 * 32 / 2;                 // bf16 counted in f32 slots
  const size_t zero_floats = off;                     // mem + spk zeroed each call
  __hip_bfloat16* actA = (__hip_bfloat16*)(ws + off); off += (size_t)4194304 / 2 * 2 / 2 + 2097152; // reserve
  // (simpler explicit arithmetic below)
  off = zero_floats;
  actA = (__hip_bfloat16*)(ws + off); off += 2097152;  // 4.19M bf16
  __hip_bfloat16* actB = (__hip_bfloat16*)(ws + off); off += 2097152;
  __hip_bfloat16* whi[8];
  __hip_bfloat16* wlo[8];
  for (int i = 0; i < 8; ++i) {
    size_t n = (size_t)Co_[i] * 9 * Cip_[i];
    whi[i] = (__hip_bfloat16*)(ws + off); off += (n + 1) / 2;
    wlo[i] = (__hip_bfloat16*)(ws + off); off += (n + 1) / 2;
  }

  // zero membranes + spike buffer (ch 3..31 stay zero all call)
  zero_f32<<<2048, 256, 0, stream>>>(ws, (int)zero_floats);
  zero_f32<<<(BB * NCLS * 1024 + 255) / 256, 256, 0, stream>>>((float*)d_out, BB * NCLS * 1024);

  // weight splits
  for (int i = 0; i < 8; ++i) {
    int n = Co_[i] * 9 * Cip_[i];
    wsplit<<<(n + 255) / 256, 256, 0, stream>>>(Wc[i], whi[i], wlo[i], Co_[i], Ci_[i], Cip_[i], wsc_[i]);
  }

  const size_t uT = (size_t)BB * 3 * 16384;
  for (int t = 0; t < TT; ++t) {
    spike_gen<<<(BB * 16384 + 255) / 256, 256, 0, stream>>>(x, u + (size_t)t * uT, spk);

    struct { const __hip_bfloat16* in; __hip_bfloat16* out; } io[8] = {
      {spk, actA}, {actA, actB}, {actA, actB}, {actB, actA},
      {actB, actA}, {actA, actB}, {actB, actA}, {actA, actB}};
    // L0
    gemm_lif<<<dim3(BB * 16384 / 64, 1), 256, 0, stream>>>(spk, whi[0], wlo[0], bn[0] + (size_t)t * 3 * 64, memp[0], actA, 32, 64, 128, 128, 1);
    // L1
    gemm_lif<<<dim3(BB * 16384 / 64, 1), 256, 0, stream>>>(actA, whi[1], wlo[1], bn[1] + (size_t)t * 3 * 64, memp[1], actB, 64, 64, 128, 128, 1);
    avgpool_sum<<<(BB * 64 * 64 * 64 + 255) / 256, 256, 0, stream>>>(actB, actA, 64, 128, 128);
    // L2 (weights pre-scaled 1/9)
    gemm_lif<<<dim3(BB * 4096 / 64, 2), 256, 0, stream>>>(actA, whi[2], wlo[2], bn[2] + (size_t)t * 3 * 128, memp[2], actB, 64, 128, 64, 64, 1);
    // L3
    gemm_lif<<<dim3(BB * 4096 / 64, 2), 256, 0, stream>>>(actB, whi[3], wlo[3], bn[3] + (size_t)t * 3 * 128, memp[3], actA, 128, 128, 64, 64, 1);
    avgpool_sum<<<(BB * 32 * 32 * 128 + 255) / 256, 256, 0, stream>>>(actA, actB, 128, 64, 64);
    // L4 (weights pre-scaled 1/9)
    gemm_lif<<<dim3(BB * 1024 / 64, 4), 256, 0, stream>>>(actB, whi[4], wlo[4], bn[4] + (size_t)t * 3 * 256, memp[4], actA, 128, 256, 32, 32, 1);
    // L5
    gemm_lif<<<dim3(BB * 1024 / 64, 4), 256, 0, stream>>>(actA, whi[5], wlo[5], bn[5] + (size_t)t * 3 * 256, memp[5], actB, 256, 256, 32, 32, 2);
    // L6
    gemm_lif<<<dim3(BB * 1024 / 64, 4), 256, 0, stream>>>(actB, whi[6], wlo[6], bn[6] + (size_t)t * 3 * 256, memp[6], actA, 256, 256, 32, 32, 2);
    // L7
    gemm_lif<<<dim3(BB * 1024 / 64, 16), 256, 0, stream>>>(actA, whi[7], wlo[7], bn[7] + (size_t)t * 3 * 1024, memp[7], actB, 256, 1024, 32, 32, 12);
    // output accumulation
    out_conv<<<dim3(BB * 1024 / 4), 256, 0, stream>>>(actB, Wc[8], (float*)d_out);
    (void)io;
  }
  scale_f32<<<(BB * NCLS * 1024 + 255) / 256, 256, 0, stream>>>((float*)d_out, BB * NCLS * 1024, 1.0f / TT);
}

// Round 3
// 3947.726 us; speedup vs baseline: 3.9755x; 1.2315x over previous
//
#include <hip/hip_runtime.h>
#include <hip/hip_bf16.h>
#include <cstddef>
#include <cstdint>

#define LEAK  0.99f
#define THRS  1.0f
#define BNEPS 1e-4f

static constexpr int TT   = 8;
static constexpr int BB   = 4;
static constexpr int NCLS = 21;

typedef __attribute__((ext_vector_type(8))) short short8v;   // 8 bf16 (MFMA A/B frag)
typedef __attribute__((ext_vector_type(4))) float f32x4;     // MFMA C/D frag

__global__ void zero_f32(float* __restrict__ p, int n) {
  int i = blockIdx.x * blockDim.x + threadIdx.x;
  int stride = gridDim.x * blockDim.x;
  for (; i < n; i += stride) p[i] = 0.0f;
}

__global__ void scale_f32(float* __restrict__ p, int n, float s) {
  int i = blockIdx.x * blockDim.x + threadIdx.x;
  if (i < n) p[i] *= s;
}

// Split f32 weights (scaled) into hi+lo bf16, reordered to k = tap*Cip + ci.
// Wsrc: [Co][Ci][9] f32.  whi/wlo: [Co][9*Cip] bf16, zero-padded ci in [Ci,Cip).
__global__ void wsplit(const float* __restrict__ Wsrc,
                       __hip_bfloat16* __restrict__ whi, __hip_bfloat16* __restrict__ wlo,
                       int Co, int Ci, int Cip, float scale) {
  const int Kpad = 9 * Cip;
  const int n = Co * Kpad;
  int i = blockIdx.x * 256 + threadIdx.x;
  if (i >= n) return;
  int co = i / Kpad, k = i - co * Kpad;
  int tap = k / Cip, ci = k - tap * Cip;
  float w = 0.0f;
  if (ci < Ci) w = Wsrc[((size_t)co * Ci + ci) * 9 + tap] * scale;
  __hip_bfloat16 h = __float2bfloat16(w);
  float r = w - __bfloat162float(h);
  whi[i] = h;
  wlo[i] = __float2bfloat16(r);
}

// Poisson generator, writes channel-last [B][HW][32] (ch 3..31 pre-zeroed once per call)
__global__ void spike_gen(const float* __restrict__ x, const float* __restrict__ u,
                          __hip_bfloat16* __restrict__ spk) {
  const int HW = 128 * 128;
  int i = blockIdx.x * 256 + threadIdx.x;  // b*HW + hw
  if (i >= BB * HW) return;
  int b = i / HW, hw = i - b * HW;
#pragma unroll
  for (int c = 0; c < 3; ++c) {
    float xv = x[((size_t)b * 3 + c) * HW + hw];
    float uv = u[((size_t)b * 3 + c) * HW + hw];
    float ax = fabsf(xv);
    float sg = (xv > 0.0f) ? 1.0f : ((xv < 0.0f) ? -1.0f : 0.0f);
    float s  = (uv <= ax) ? sg : 0.0f;
    spk[(size_t)i * 32 + c] = __float2bfloat16(s);
  }
}

// Implicit-GEMM conv3x3(pad==dil) + BN + LIF.  MFMA 16x16x32 bf16, hi+lo weight split.
// actin : [B*HW][Cip] bf16 (channel-last)   wsp: [2][Co][Kpad] bf16 (hi then lo)
// mem   : [B*HW][Co] f32                    actout: [B*HW][Co] bf16 (spikes)
// Wave tile 64px x 64co (acc 4x4 frags). Block = NW waves px-stacked: NW*64 px x 64 co.
// Weights LDS-staged per K-chunk of 32, double-buffered, slot-swizzled.
template<int NW>
__global__ __launch_bounds__(NW * 64) void gemm_lif(
    const __hip_bfloat16* __restrict__ actin,
    const __hip_bfloat16* __restrict__ wsp,
    const float* __restrict__ bnt,        // [3][Co] for this timestep
    float* __restrict__ mem, __hip_bfloat16* __restrict__ actout,
    int Cip, int Co, int lgHW, int lgW, int dil) {
  __shared__ __hip_bfloat16 lds[2 * 128 * 32];   // 2 bufs x (64co hi + 64co lo) x 64B
  const int HW = 1 << lgHW;
  const int H  = HW >> lgW;
  const int W  = 1 << lgW;
  const int Kpad = 9 * Cip;
  const int lane = threadIdx.x & 63, wid = threadIdx.x >> 6;
  const int l15 = lane & 15, g = lane >> 4;
  const int p0  = (blockIdx.x * NW + wid) << 6;
  const int co0 = blockIdx.y << 6;

  // per-m-frag pixel decompose (16 consecutive px stay in one image row: W%16==0)
  int b_[4], y_[4], x_[4];
#pragma unroll
  for (int bi = 0; bi < 4; ++bi) {
    int pb = p0 + bi * 16;
    b_[bi] = pb >> lgHW;
    int rem = pb & (HW - 1);
    y_[bi] = rem >> lgW;
    x_[bi] = (rem & (W - 1)) + l15;
  }

  // weight staging: 128 rows (64 hi + 64 lo) of 64B per chunk; 16 rows per wave-inst.
  // LDS dest is linear (base + lane*16); swizzle applied on the GLOBAL source so that
  // LDS slot s of row co holds global slot s ^ ((co>>1)&3).
  constexpr int INSTS = 8 / NW;
  const int r_base = wid * (128 / NW);
  size_t sg[INSTS];
#pragma unroll
  for (int i = 0; i < INSTS; ++i) {
    int row = r_base + i * 16 + (lane >> 2);
    int isl = row >> 6;          // 0 = hi, 1 = lo
    int co  = row & 63;
    int slot = (lane & 3) ^ ((co >> 1) & 3);
    sg[i] = (size_t)isl * Co * Kpad + (size_t)(co0 + co) * Kpad + slot * 8;
  }

  auto stage = [&](int buf, int kk) {
#pragma unroll
    for (int i = 0; i < INSTS; ++i) {
      const __hip_bfloat16* gp = wsp + sg[i] + kk;
      __hip_bfloat16* lp = &lds[buf * 4096 + (r_base + i * 16) * 32];
      __builtin_amdgcn_global_load_lds(
          (const __attribute__((address_space(1))) void*)gp,
          (__attribute__((address_space(3))) void*)lp, 16, 0, 0);
    }
  };

  f32x4 acc[4][4] = {};
  const int cpt = Cip >> 5;        // K-chunks per tap
  const int NC  = 9 * cpt;
  // swizzled read offset: row = j*16 + l15, want k-group g -> slot g ^ ((row>>1)&3)
  // (j*16 contributes 0 mod 4 to (row>>1)&3, so j-independent)
  const int rd0 = l15 * 32 + ((g ^ ((l15 >> 1) & 3)) * 8);

  stage(0, 0);
  __syncthreads();

  int cur = 0, chunk = 0;
  for (int tap = 0; tap < 9; ++tap) {
    const int dy = (tap / 3 - 1) * dil, dx = (tap % 3 - 1) * dil;
    const __hip_bfloat16* ap[4];
    bool av[4];
#pragma unroll
    for (int bi = 0; bi < 4; ++bi) {
      int sy = y_[bi] + dy, sx = x_[bi] + dx;
      bool v = (sy >= 0) & (sy < H) & (sx >= 0) & (sx < W);
      av[bi] = v;
      int pix = v ? ((b_[bi] << lgHW) + (sy << lgW) + sx) : 0;
      ap[bi] = actin + (size_t)pix * Cip + 8 * g;
    }
    for (int kc = 0; kc < Cip; kc += 32) {
      if (chunk + 1 < NC) stage(cur ^ 1, (chunk + 1) * 32);

      const short8v zz = {};
      short8v a[4];
#pragma unroll
      for (int bi = 0; bi < 4; ++bi) {
        short8v t = *(const short8v*)(ap[bi] + kc);
        a[bi] = av[bi] ? t : zz;
      }
      const __hip_bfloat16* bp = &lds[cur * 4096];
      short8v bh[4], bl[4];
#pragma unroll
      for (int j = 0; j < 4; ++j) {
        bh[j] = *(const short8v*)(bp + j * 512 + rd0);
        bl[j] = *(const short8v*)(bp + 2048 + j * 512 + rd0);
      }
#pragma unroll
      for (int j = 0; j < 4; ++j)
#pragma unroll
        for (int bi = 0; bi < 4; ++bi) {
          acc[bi][j] = __builtin_amdgcn_mfma_f32_16x16x32_bf16(a[bi], bh[j], acc[bi][j], 0, 0, 0);
          acc[bi][j] = __builtin_amdgcn_mfma_f32_16x16x32_bf16(a[bi], bl[j], acc[bi][j], 0, 0, 0);
        }
      __syncthreads();
      cur ^= 1; ++chunk;
    }
  }

  // epilogue: BN + LIF.  D layout: co = co0 + j*16 + l15, pixel = p0 + bi*16 + 4g + r
#pragma unroll
  for (int j = 0; j < 4; ++j) {
    int c = co0 + j * 16 + l15;
    float ga = bnt[c], mu = bnt[Co + c], va = bnt[2 * Co + c];
    float sc = ga / sqrtf(va + BNEPS);
#pragma unroll
    for (int bi = 0; bi < 4; ++bi) {
      int pixb = p0 + bi * 16 + 4 * g;
#pragma unroll
      for (int r = 0; r < 4; ++r) {
        size_t idx = (size_t)(pixb + r) * Co + c;
        float bno = (acc[bi][j][r] - mu) * sc;
        float m = LEAK * mem[idx] + bno;
        float s = (m > THRS) ? 1.0f : 0.0f;
        actout[idx] = __float2bfloat16(s);
        mem[idx] = m - s;
      }
    }
  }
}

// AvgPool(3,2,1) storing SUM (exact ints in bf16); /9 folded into next layer's weights.
__global__ void avgpool_sum(const __hip_bfloat16* __restrict__ in, __hip_bfloat16* __restrict__ out,
                            int C, int H, int W) {
  const int Ho = H >> 1, Wo = W >> 1;
  const int n = BB * Ho * Wo * C;
  int i = blockIdx.x * 256 + threadIdx.x;
  if (i >= n) return;
  int c = i % C; int t = i / C;
  int xo = t % Wo; t /= Wo;
  int yo = t % Ho; int b = t / Ho;
  const int y0 = 2 * yo - 1, x0 = 2 * xo - 1;
  float s = 0.0f;
#pragma unroll
  for (int dy = 0; dy < 3; ++dy) {
    int iy = y0 + dy;
    if (iy < 0 || iy >= H) continue;
#pragma unroll
    for (int dx = 0; dx < 3; ++dx) {
      int ix = x0 + dx;
      if (ix < 0 || ix >= W) continue;
      s += __bfloat162float(in[(((size_t)b * H + iy) * W + ix) * C + c]);
    }
  }
  out[i] = __float2bfloat16(s);
}

// 1x1 conv 1024->21 @32x32, f32, accumulate into d_out. One wave per (b,pix).
__global__ void out_conv(const __hip_bfloat16* __restrict__ act,  // [B*1024px][1024ch]
                         const float* __restrict__ W8, float* __restrict__ out) {
  int gw = (blockIdx.x * 256 + threadIdx.x) >> 6;  // b*1024 + pix
  int lane = threadIdx.x & 63;
  int b = gw >> 10, pix = gw & 1023;
  const __hip_bfloat16* ap = act + ((size_t)gw << 10);
  float acc[NCLS];
#pragma unroll
  for (int c = 0; c < NCLS; ++c) acc[c] = 0.0f;
  for (int j = 0; j < 16; ++j) {
    int ci = j * 64 + lane;
    float av = __bfloat162float(ap[ci]);
#pragma unroll
    for (int c = 0; c < NCLS; ++c) acc[c] = fmaf(av, W8[c * 1024 + ci], acc[c]);
  }
#pragma unroll
  for (int c = 0; c < NCLS; ++c) {
    float v = acc[c];
    for (int off = 32; off; off >>= 1) v += __shfl_xor(v, off, 64);
    if (lane == 0) out[((size_t)b * NCLS + c) * 1024 + pix] += v;
  }
}

extern "C" void kernel_launch(void* const* d_in, const int* in_sizes, int n_in,
                              void* d_out, int out_size, void* d_ws, size_t ws_size,
                              hipStream_t stream) {
  const float* x = (const float*)d_in[0];
  const float* u = (const float*)d_in[1];
  const float* Wc[9];
  for (int i = 0; i < 9; ++i) Wc[i] = (const float*)d_in[2 + i];
  const float* bn[8];
  for (int i = 0; i < 8; ++i) bn[i] = (const float*)d_in[11 + i];

  const int Ci_[8]  = {3, 64, 64, 128, 128, 256, 256, 256};
  const int Cip_[8] = {32, 64, 64, 128, 128, 256, 256, 256};
  const int Co_[8]  = {64, 64, 128, 128, 256, 256, 256, 1024};
  const int HH_[8]  = {128, 128, 64, 64, 32, 32, 32, 32};
  const float wsc_[8] = {1.f, 1.f, 1.f / 9.f, 1.f, 1.f / 9.f, 1.f, 1.f, 1.f};

  float* ws = (float*)d_ws;
  size_t off = 0;
  auto align8 = [](size_t v) { return (v + 7) & ~(size_t)7; };

  float* memp[8];
  for (int i = 0; i < 8; ++i) {
    memp[i] = ws + off;
    off += (size_t)BB * HH_[i] * HH_[i] * Co_[i];
  }
  __hip_bfloat16* spk = (__hip_bfloat16*)(ws + off);
  off += (size_t)BB * 16384 * 32 / 2;
  const size_t zero_floats = off;                       // mem + spk zeroed each call
  __hip_bfloat16* actA = (__hip_bfloat16*)(ws + off); off += 2097152;
  __hip_bfloat16* actB = (__hip_bfloat16*)(ws + off); off += 2097152;
  __hip_bfloat16* wall[8];
  for (int i = 0; i < 8; ++i) {
    size_t n = (size_t)Co_[i] * 9 * Cip_[i];            // per half
    wall[i] = (__hip_bfloat16*)(ws + off);
    off = align8(off + n);                              // hi + lo = 2n bf16 = n floats
  }

  zero_f32<<<2048, 256, 0, stream>>>(ws, (int)zero_floats);
  zero_f32<<<(BB * NCLS * 1024 + 255) / 256, 256, 0, stream>>>((float*)d_out, BB * NCLS * 1024);

  for (int i = 0; i < 8; ++i) {
    int n = Co_[i] * 9 * Cip_[i];
    wsplit<<<(n + 255) / 256, 256, 0, stream>>>(Wc[i], wall[i], wall[i] + n,
                                                Co_[i], Ci_[i], Cip_[i], wsc_[i]);
  }

  const size_t uT = (size_t)BB * 3 * 16384;
  for (int t = 0; t < TT; ++t) {
    spike_gen<<<(BB * 16384 + 255) / 256, 256, 0, stream>>>(x, u + (size_t)t * uT, spk);
    // L0: 3(32)->64 @128
    gemm_lif<4><<<dim3(256, 1), 256, 0, stream>>>(spk,  wall[0], bn[0] + (size_t)t * 3 * 64,   memp[0], actA, 32,  64,   14, 7, 1);
    // L1: 64->64 @128
    gemm_lif<4><<<dim3(256, 1), 256, 0, stream>>>(actA, wall[1], bn[1] + (size_t)t * 3 * 64,   memp[1], actB, 64,  64,   14, 7, 1);
    avgpool_sum<<<(BB * 64 * 64 * 64 + 255) / 256, 256, 0, stream>>>(actB, actA, 64, 128, 128);
    // L2: 64->128 @64 (weights pre-scaled 1/9)
    gemm_lif<2><<<dim3(128, 2), 128, 0, stream>>>(actA, wall[2], bn[2] + (size_t)t * 3 * 128,  memp[2], actB, 64,  128,  12, 6, 1);
    // L3: 128->128 @64
    gemm_lif<2><<<dim3(128, 2), 128, 0, stream>>>(actB, wall[3], bn[3] + (size_t)t * 3 * 128,  memp[3], actA, 128, 128,  12, 6, 1);
    avgpool_sum<<<(BB * 32 * 32 * 128 + 255) / 256, 256, 0, stream>>>(actA, actB, 128, 64, 64);
    // L4: 128->256 @32 (weights pre-scaled 1/9)
    gemm_lif<2><<<dim3(32, 4), 128, 0, stream>>>(actB, wall[4], bn[4] + (size_t)t * 3 * 256,   memp[4], actA, 128, 256,  10, 5, 1);
    // L5: 256->256 @32 dil2
    gemm_lif<2><<<dim3(32, 4), 128, 0, stream>>>(actA, wall[5], bn[5] + (size_t)t * 3 * 256,   memp[5], actB, 256, 256,  10, 5, 2);
    // L6: 256->256 @32 dil2
    gemm_lif<2><<<dim3(32, 4), 128, 0, stream>>>(actB, wall[6], bn[6] + (size_t)t * 3 * 256,   memp[6], actA, 256, 256,  10, 5, 2);
    // L7: 256->1024 @32 dil12
    gemm_lif<4><<<dim3(16, 16), 256, 0, stream>>>(actA, wall[7], bn[7] + (size_t)t * 3 * 1024, memp[7], actB, 256, 1024, 10, 5, 12);
    // output layer accumulation
    out_conv<<<dim3(BB * 1024 / 4), 256, 0, stream>>>(actB, Wc[8], (float*)d_out);
  }
  scale_f32<<<(BB * NCLS * 1024 + 255) / 256, 256, 0, stream>>>((float*)d_out, BB * NCLS * 1024, 1.0f / TT);
}

// Round 4
// 3778.828 us; speedup vs baseline: 4.1532x; 1.0447x over previous
//
#include <hip/hip_runtime.h>
#include <hip/hip_bf16.h>
#include <cstddef>
#include <cstdint>

#define LEAK  0.99f
#define THRS  1.0f
#define BNEPS 1e-4f

static constexpr int TT   = 8;
static constexpr int BB   = 4;
static constexpr int NCLS = 21;

typedef __attribute__((ext_vector_type(8))) short short8v;   // 8 bf16 (MFMA A/B frag)
typedef __attribute__((ext_vector_type(4))) float f32x4;     // MFMA C/D frag

__global__ void zero_f32(float* __restrict__ p, int n) {
  int i = blockIdx.x * blockDim.x + threadIdx.x;
  int stride = gridDim.x * blockDim.x;
  for (; i < n; i += stride) p[i] = 0.0f;
}

__global__ void scale_f32(float* __restrict__ p, int n, float s) {
  int i = blockIdx.x * blockDim.x + threadIdx.x;
  if (i < n) p[i] *= s;
}

// Split f32 weights (scaled) into hi+lo bf16, reordered to k = tap*Cip + ci.
// Wsrc: [Co][Ci][9] f32.  whi/wlo: [Co][9*Cip] bf16, zero-padded ci in [Ci,Cip).
__global__ void wsplit(const float* __restrict__ Wsrc,
                       __hip_bfloat16* __restrict__ whi, __hip_bfloat16* __restrict__ wlo,
                       int Co, int Ci, int Cip, float scale) {
  const int Kpad = 9 * Cip;
  const int n = Co * Kpad;
  int i = blockIdx.x * 256 + threadIdx.x;
  if (i >= n) return;
  int co = i / Kpad, k = i - co * Kpad;
  int tap = k / Cip, ci = k - tap * Cip;
  float w = 0.0f;
  if (ci < Ci) w = Wsrc[((size_t)co * Ci + ci) * 9 + tap] * scale;
  __hip_bfloat16 h = __float2bfloat16(w);
  float r = w - __bfloat162float(h);
  whi[i] = h;
  wlo[i] = __float2bfloat16(r);
}

// Poisson generator, writes channel-last [B][HW][32] (ch 3..31 pre-zeroed each call)
__global__ void spike_gen(const float* __restrict__ x, const float* __restrict__ u,
                          __hip_bfloat16* __restrict__ spk) {
  const int HW = 128 * 128;
  int i = blockIdx.x * 256 + threadIdx.x;  // b*HW + hw
  if (i >= BB * HW) return;
  int b = i / HW, hw = i - b * HW;
#pragma unroll
  for (int c = 0; c < 3; ++c) {
    float xv = x[((size_t)b * 3 + c) * HW + hw];
    float uv = u[((size_t)b * 3 + c) * HW + hw];
    float ax = fabsf(xv);
    float sg = (xv > 0.0f) ? 1.0f : ((xv < 0.0f) ? -1.0f : 0.0f);
    float s  = (uv <= ax) ? sg : 0.0f;
    spk[(size_t)i * 32 + c] = __float2bfloat16(s);
  }
}

// Implicit-GEMM conv3x3(pad==dil) + BN + LIF.  MFMA 16x16x32 bf16, hi+lo weight split.
// actin : [B*HW][Cip] bf16 (channel-last)   wsp: [2][Co][Kpad] bf16 (hi then lo)
// mem   : [B*HW][Co] f32                    actout: [B*HW][Co] bf16 (spikes)
// Wave tile 64px x 64co (acc 4x4 frags). Block = NW waves px-stacked.
// 2-phase pipeline: barrier at top of chunk; weights LDS-double-buffered one chunk
// ahead (global_load_lds); A-fragments register-prefetched one chunk ahead.
template<int NW>
__global__ __launch_bounds__(NW * 64) void gemm_lif(
    const __hip_bfloat16* __restrict__ actin,
    const __hip_bfloat16* __restrict__ wsp,
    const float* __restrict__ bnt,        // [3][Co] for this timestep
    float* __restrict__ mem, __hip_bfloat16* __restrict__ actout,
    int Cip, int Co, int lgHW, int lgW, int dil) {
  __shared__ __hip_bfloat16 lds[2 * 128 * 32];   // 2 bufs x (64co hi + 64co lo) x 64B
  const int HW = 1 << lgHW;
  const int H  = HW >> lgW;
  const int W  = 1 << lgW;
  const int Kpad = 9 * Cip;
  const int lane = threadIdx.x & 63, wid = threadIdx.x >> 6;
  const int l15 = lane & 15, g = lane >> 4;
  const int p0  = (blockIdx.x * NW + wid) << 6;
  const int co0 = blockIdx.y << 6;

  // per-m-frag pixel decompose (16 consecutive px stay in one image row: W%16==0)
  int b_[4], y_[4], x_[4];
#pragma unroll
  for (int bi = 0; bi < 4; ++bi) {
    int pb = p0 + bi * 16;
    b_[bi] = pb >> lgHW;
    int rem = pb & (HW - 1);
    y_[bi] = rem >> lgW;
    x_[bi] = (rem & (W - 1)) + l15;
  }

  // weight staging: 128 rows (64 hi + 64 lo) of 64B per chunk; 16 rows per wave-inst.
  // LDS dest is linear (base + lane*16); swizzle applied on the GLOBAL source so that
  // LDS slot s of row co holds global slot s ^ ((co>>1)&3).
  constexpr int INSTS = 8 / NW;
  const int r_base = wid * (128 / NW);
  size_t sg[INSTS];
#pragma unroll
  for (int i = 0; i < INSTS; ++i) {
    int row = r_base + i * 16 + (lane >> 2);
    int isl = row >> 6;          // 0 = hi, 1 = lo
    int co  = row & 63;
    int slot = (lane & 3) ^ ((co >> 1) & 3);
    sg[i] = (size_t)isl * Co * Kpad + (size_t)(co0 + co) * Kpad + slot * 8;
  }

  auto stage = [&](int buf, int kk) {
#pragma unroll
    for (int i = 0; i < INSTS; ++i) {
      const __hip_bfloat16* gp = wsp + sg[i] + kk;
      __hip_bfloat16* lp = &lds[buf * 4096 + (r_base + i * 16) * 32];
      __builtin_amdgcn_global_load_lds(
          (const __attribute__((address_space(1))) void*)gp,
          (__attribute__((address_space(3))) void*)lp, 16, 0, 0);
    }
  };

  f32x4 acc[4][4] = {};
  const int cpt = Cip >> 5;        // K-chunks per tap (1,2,4,8)
  const int lgcpt = __builtin_ctz(cpt);
  const int NC  = 9 * cpt;
  // swizzled read offset: row = j*16 + l15, k-group g -> slot g ^ ((row>>1)&3)
  const int rd0 = l15 * 32 + ((g ^ ((l15 >> 1) & 3)) * 8);

  // per-tap A addressing (regenerated at tap boundaries only; wave-uniform branch)
  const __hip_bfloat16* apc[4];
  bool avc[4];
  auto mkaddr = [&](int tap) {
    int ty = (tap * 11) >> 5;          // tap/3 for 0..8
    int tx = tap - ty * 3;
    int dy = (ty - 1) * dil, dx = (tx - 1) * dil;
#pragma unroll
    for (int bi = 0; bi < 4; ++bi) {
      int sy = y_[bi] + dy, sx = x_[bi] + dx;
      bool v = (sy >= 0) & (sy < H) & (sx >= 0) & (sx < W);
      avc[bi] = v;
      int pix = v ? ((b_[bi] << lgHW) + (sy << lgW) + sx) : 0;
      apc[bi] = actin + (size_t)pix * Cip + 8 * g;
    }
  };

  const short8v zz = {};
  short8v a_cur[4], a_next[4];

  // prologue: stage chunk 0, prefetch A for chunk 0
  stage(0, 0);
  mkaddr(0);
#pragma unroll
  for (int bi = 0; bi < 4; ++bi) {
    short8v t = *(const short8v*)(apc[bi]);
    a_cur[bi] = avc[bi] ? t : zz;
  }

  for (int c = 0; c < NC; ++c) {
    __syncthreads();   // drains my stage(c)+Apf(c) (issued a full chunk ago) + barrier

    // LDS reads for current chunk (buffer c&1)
    const __hip_bfloat16* bp = &lds[(c & 1) * 4096];
    short8v bh[4], bl[4];
#pragma unroll
    for (int j = 0; j < 4; ++j) {
      bh[j] = *(const short8v*)(bp + j * 512 + rd0);
      bl[j] = *(const short8v*)(bp + 2048 + j * 512 + rd0);
    }

    // prefetch next chunk: weights -> LDS (other buffer), A -> registers
    if (c + 1 < NC) {
      stage((c + 1) & 1, (c + 1) * 32);
      const int c1 = c + 1;
      const int kc1 = (c1 & (cpt - 1)) << 5;
      if (kc1 == 0) mkaddr(c1 >> lgcpt);
#pragma unroll
      for (int bi = 0; bi < 4; ++bi) {
        short8v t = *(const short8v*)(apc[bi] + kc1);
        a_next[bi] = avc[bi] ? t : zz;
      }
    }

    // MFMA: order per accumulator identical to prior rounds (hi then lo per chunk)
#pragma unroll
    for (int j = 0; j < 4; ++j)
#pragma unroll
      for (int bi = 0; bi < 4; ++bi) {
        acc[bi][j] = __builtin_amdgcn_mfma_f32_16x16x32_bf16(a_cur[bi], bh[j], acc[bi][j], 0, 0, 0);
        acc[bi][j] = __builtin_amdgcn_mfma_f32_16x16x32_bf16(a_cur[bi], bl[j], acc[bi][j], 0, 0, 0);
      }
#pragma unroll
    for (int bi = 0; bi < 4; ++bi) a_cur[bi] = a_next[bi];
  }

  // epilogue: BN + LIF.  D layout: co = co0 + j*16 + l15, pixel = p0 + bi*16 + 4g + r
#pragma unroll
  for (int j = 0; j < 4; ++j) {
    int c = co0 + j * 16 + l15;
    float ga = bnt[c], mu = bnt[Co + c], va = bnt[2 * Co + c];
    float sc = ga / sqrtf(va + BNEPS);
#pragma unroll
    for (int bi = 0; bi < 4; ++bi) {
      int pixb = p0 + bi * 16 + 4 * g;
#pragma unroll
      for (int r = 0; r < 4; ++r) {
        size_t idx = (size_t)(pixb + r) * Co + c;
        float bno = (acc[bi][j][r] - mu) * sc;
        float m = LEAK * mem[idx] + bno;
        float s = (m > THRS) ? 1.0f : 0.0f;
        actout[idx] = __float2bfloat16(s);
        mem[idx] = m - s;
      }
    }
  }
}

// AvgPool(3,2,1) storing SUM (exact ints in bf16); /9 folded into next layer's weights.
__global__ void avgpool_sum(const __hip_bfloat16* __restrict__ in, __hip_bfloat16* __restrict__ out,
                            int C, int H, int W) {
  const int Ho = H >> 1, Wo = W >> 1;
  const int n = BB * Ho * Wo * C;
  int i = blockIdx.x * 256 + threadIdx.x;
  if (i >= n) return;
  int c = i % C; int t = i / C;
  int xo = t % Wo; t /= Wo;
  int yo = t % Ho; int b = t / Ho;
  const int y0 = 2 * yo - 1, x0 = 2 * xo - 1;
  float s = 0.0f;
#pragma unroll
  for (int dy = 0; dy < 3; ++dy) {
    int iy = y0 + dy;
    if (iy < 0 || iy >= H) continue;
#pragma unroll
    for (int dx = 0; dx < 3; ++dx) {
      int ix = x0 + dx;
      if (ix < 0 || ix >= W) continue;
      s += __bfloat162float(in[(((size_t)b * H + iy) * W + ix) * C + c]);
    }
  }
  out[i] = __float2bfloat16(s);
}

// 1x1 conv 1024->21 @32x32, f32, accumulate into d_out. One wave per (b,pix).
__global__ void out_conv(const __hip_bfloat16* __restrict__ act,  // [B*1024px][1024ch]
                         const float* __restrict__ W8, float* __restrict__ out) {
  int gw = (blockIdx.x * 256 + threadIdx.x) >> 6;  // b*1024 + pix
  int lane = threadIdx.x & 63;
  int b = gw >> 10, pix = gw & 1023;
  const __hip_bfloat16* ap = act + ((size_t)gw << 10);
  float acc[NCLS];
#pragma unroll
  for (int c = 0; c < NCLS; ++c) acc[c] = 0.0f;
  for (int j = 0; j < 16; ++j) {
    int ci = j * 64 + lane;
    float av = __bfloat162float(ap[ci]);
#pragma unroll
    for (int c = 0; c < NCLS; ++c) acc[c] = fmaf(av, W8[c * 1024 + ci], acc[c]);
  }
#pragma unroll
  for (int c = 0; c < NCLS; ++c) {
    float v = acc[c];
    for (int off = 32; off; off >>= 1) v += __shfl_xor(v, off, 64);
    if (lane == 0) out[((size_t)b * NCLS + c) * 1024 + pix] += v;
  }
}

extern "C" void kernel_launch(void* const* d_in, const int* in_sizes, int n_in,
                              void* d_out, int out_size, void* d_ws, size_t ws_size,
                              hipStream_t stream) {
  const float* x = (const float*)d_in[0];
  const float* u = (const float*)d_in[1];
  const float* Wc[9];
  for (int i = 0; i < 9; ++i) Wc[i] = (const float*)d_in[2 + i];
  const float* bn[8];
  for (int i = 0; i < 8; ++i) bn[i] = (const float*)d_in[11 + i];

  const int Ci_[8]  = {3, 64, 64, 128, 128, 256, 256, 256};
  const int Cip_[8] = {32, 64, 64, 128, 128, 256, 256, 256};
  const int Co_[8]  = {64, 64, 128, 128, 256, 256, 256, 1024};
  const int HH_[8]  = {128, 128, 64, 64, 32, 32, 32, 32};
  const float wsc_[8] = {1.f, 1.f, 1.f / 9.f, 1.f, 1.f / 9.f, 1.f, 1.f, 1.f};

  float* ws = (float*)d_ws;
  size_t off = 0;
  auto align8 = [](size_t v) { return (v + 7) & ~(size_t)7; };

  float* memp[8];
  for (int i = 0; i < 8; ++i) {
    memp[i] = ws + off;
    off += (size_t)BB * HH_[i] * HH_[i] * Co_[i];
  }
  __hip_bfloat16* spk = (__hip_bfloat16*)(ws + off);
  off += (size_t)BB * 16384 * 32 / 2;
  const size_t zero_floats = off;                       // mem + spk zeroed each call
  __hip_bfloat16* actA = (__hip_bfloat16*)(ws + off); off += 2097152;
  __hip_bfloat16* actB = (__hip_bfloat16*)(ws + off); off += 2097152;
  __hip_bfloat16* wall[8];
  for (int i = 0; i < 8; ++i) {
    size_t n = (size_t)Co_[i] * 9 * Cip_[i];            // per half
    wall[i] = (__hip_bfloat16*)(ws + off);
    off = align8(off + n);                              // hi + lo = 2n bf16 = n floats
  }

  zero_f32<<<2048, 256, 0, stream>>>(ws, (int)zero_floats);
  zero_f32<<<(BB * NCLS * 1024 + 255) / 256, 256, 0, stream>>>((float*)d_out, BB * NCLS * 1024);

  for (int i = 0; i < 8; ++i) {
    int n = Co_[i] * 9 * Cip_[i];
    wsplit<<<(n + 255) / 256, 256, 0, stream>>>(Wc[i], wall[i], wall[i] + n,
                                                Co_[i], Ci_[i], Cip_[i], wsc_[i]);
  }

  const size_t uT = (size_t)BB * 3 * 16384;
  for (int t = 0; t < TT; ++t) {
    spike_gen<<<(BB * 16384 + 255) / 256, 256, 0, stream>>>(x, u + (size_t)t * uT, spk);
    // L0: 3(32)->64 @128
    gemm_lif<4><<<dim3(256, 1), 256, 0, stream>>>(spk,  wall[0], bn[0] + (size_t)t * 3 * 64,   memp[0], actA, 32,  64,   14, 7, 1);
    // L1: 64->64 @128
    gemm_lif<4><<<dim3(256, 1), 256, 0, stream>>>(actA, wall[1], bn[1] + (size_t)t * 3 * 64,   memp[1], actB, 64,  64,   14, 7, 1);
    avgpool_sum<<<(BB * 64 * 64 * 64 + 255) / 256, 256, 0, stream>>>(actB, actA, 64, 128, 128);
    // L2: 64->128 @64 (weights pre-scaled 1/9) — 256 blocks
    gemm_lif<2><<<dim3(128, 2), 128, 0, stream>>>(actA, wall[2], bn[2] + (size_t)t * 3 * 128,  memp[2], actB, 64,  128,  12, 6, 1);
    // L3: 128->128 @64 — 256 blocks
    gemm_lif<2><<<dim3(128, 2), 128, 0, stream>>>(actB, wall[3], bn[3] + (size_t)t * 3 * 128,  memp[3], actA, 128, 128,  12, 6, 1);
    avgpool_sum<<<(BB * 32 * 32 * 128 + 255) / 256, 256, 0, stream>>>(actA, actB, 128, 64, 64);
    // L4: 128->256 @32 (weights pre-scaled 1/9) — 256 single-wave blocks
    gemm_lif<1><<<dim3(64, 4), 64, 0, stream>>>(actB, wall[4], bn[4] + (size_t)t * 3 * 256,   memp[4], actA, 128, 256,  10, 5, 1);
    // L5: 256->256 @32 dil2
    gemm_lif<1><<<dim3(64, 4), 64, 0, stream>>>(actA, wall[5], bn[5] + (size_t)t * 3 * 256,   memp[5], actB, 256, 256,  10, 5, 2);
    // L6: 256->256 @32 dil2
    gemm_lif<1><<<dim3(64, 4), 64, 0, stream>>>(actB, wall[6], bn[6] + (size_t)t * 3 * 256,   memp[6], actA, 256, 256,  10, 5, 2);
    // L7: 256->1024 @32 dil12
    gemm_lif<4><<<dim3(16, 16), 256, 0, stream>>>(actA, wall[7], bn[7] + (size_t)t * 3 * 1024, memp[7], actB, 256, 1024, 10, 5, 12);
    // output layer accumulation
    out_conv<<<dim3(BB * 1024 / 4), 256, 0, stream>>>(actB, Wc[8], (float*)d_out);
  }
  scale_f32<<<(BB * NCLS * 1024 + 255) / 256, 256, 0, stream>>>((float*)d_out, BB * NCLS * 1024, 1.0f / TT);
}

// Round 5
// 2110.033 us; speedup vs baseline: 7.4378x; 1.7909x over previous
//
#include <hip/hip_runtime.h>
#include <hip/hip_bf16.h>
#include <cstddef>
#include <cstdint>

#define LEAK  0.99f
#define THRS  1.0f
#define BNEPS 1e-4f

static constexpr int TT   = 8;
static constexpr int BB   = 4;
static constexpr int NCLS = 21;

typedef __attribute__((ext_vector_type(8))) short short8v;   // 8 bf16 (MFMA A/B frag)
typedef __attribute__((ext_vector_type(4))) float f32x4;     // MFMA C/D frag

__global__ void zero_f32(float* __restrict__ p, int n) {
  int i = blockIdx.x * blockDim.x + threadIdx.x;
  int stride = gridDim.x * blockDim.x;
  for (; i < n; i += stride) p[i] = 0.0f;
}

__global__ void scale_f32(float* __restrict__ p, int n, float s) {
  int i = blockIdx.x * blockDim.x + threadIdx.x;
  if (i < n) p[i] *= s;
}

// Split f32 weights (scaled) into hi+lo bf16, reordered to k = tap*Cip + ci.
__global__ void wsplit(const float* __restrict__ Wsrc,
                       __hip_bfloat16* __restrict__ whi, __hip_bfloat16* __restrict__ wlo,
                       int Co, int Ci, int Cip, float scale) {
  const int Kpad = 9 * Cip;
  const int n = Co * Kpad;
  int i = blockIdx.x * 256 + threadIdx.x;
  if (i >= n) return;
  int co = i / Kpad, k = i - co * Kpad;
  int tap = k / Cip, ci = k - tap * Cip;
  float w = 0.0f;
  if (ci < Ci) w = Wsrc[((size_t)co * Ci + ci) * 9 + tap] * scale;
  __hip_bfloat16 h = __float2bfloat16(w);
  float r = w - __bfloat162float(h);
  whi[i] = h;
  wlo[i] = __float2bfloat16(r);
}

// Poisson generator, writes channel-last [B][HW][32] (ch 3..31 pre-zeroed each call)
__global__ void spike_gen(const float* __restrict__ x, const float* __restrict__ u,
                          __hip_bfloat16* __restrict__ spk) {
  const int HW = 128 * 128;
  int i = blockIdx.x * 256 + threadIdx.x;  // b*HW + hw
  if (i >= BB * HW) return;
  int b = i / HW, hw = i - b * HW;
#pragma unroll
  for (int c = 0; c < 3; ++c) {
    float xv = x[((size_t)b * 3 + c) * HW + hw];
    float uv = u[((size_t)b * 3 + c) * HW + hw];
    float ax = fabsf(xv);
    float sg = (xv > 0.0f) ? 1.0f : ((xv < 0.0f) ? -1.0f : 0.0f);
    float s  = (uv <= ax) ? sg : 0.0f;
    spk[(size_t)i * 32 + c] = __float2bfloat16(s);
  }
}

// Implicit-GEMM conv3x3(pad==dil) + BN + LIF.  MFMA 16x16x32 bf16, hi+lo weight split.
// Wave tile (M*16 px) x (N*16 co); block = 4 waves px-stacked.
// Group pipeline: barrier per GRP chunks; group-top burst issues next group's
// weight staging (global_load_lds, LDS double-buffered) AND A-register prefetch,
// so the __syncthreads vmcnt(0) drain lands a full group of compute after issue.
template<int M, int N, int GRP>
__global__ __launch_bounds__(256) void gemm_lif(
    const __hip_bfloat16* __restrict__ actin,
    const __hip_bfloat16* __restrict__ wsp,      // [2][Co][Kpad] hi, lo
    const float* __restrict__ bnt,               // [3][Co] for this timestep
    float* __restrict__ mem, __hip_bfloat16* __restrict__ actout,
    int Cip, int Co, int lgHW, int lgW, int dil, int lgGX) {
  constexpr int NW = 4;
  constexpr int R  = N * 32;                 // LDS rows per chunk (hi+lo halves)
  constexpr int BUFROWS = GRP * R;
  constexpr int BUFELEM = BUFROWS * 32;      // bf16 elems per buffer
  constexpr int INSTS = BUFROWS / (16 * NW); // global_load_lds per wave per group
  __shared__ __hip_bfloat16 lds[2 * BUFELEM];

  const int HW = 1 << lgHW, H = HW >> lgW, W = 1 << lgW;
  const int Kpad = 9 * Cip;
  const size_t CoKpad = (size_t)Co * Kpad;
  const int lane = threadIdx.x & 63, wid = threadIdx.x >> 6;
  const int l15 = lane & 15, g = lane >> 4;

  // XCD-chunked bijective block swizzle (gridDim.x % 8 == 0)
  const int nb = gridDim.x;
  const int flat = blockIdx.x;
  const int swz = (flat & 7) * (nb >> 3) + (flat >> 3);
  const int bx = swz & ((1 << lgGX) - 1);
  const int by = swz >> lgGX;
  const int p0  = (bx * NW + wid) * (M * 16);
  const int co0 = by * (N * 16);

  // per-m-frag pixel decompose (16 consecutive px stay in one image row: W>=16)
  int b_[M], y_[M], x_[M];
#pragma unroll
  for (int m = 0; m < M; ++m) {
    int pb = p0 + m * 16;
    b_[m] = pb >> lgHW;
    int rem = pb & (HW - 1);
    y_[m] = rem >> lgW;
    x_[m] = (rem & (W - 1)) + l15;
  }

  // weight staging source addrs (LDS dest linear; swizzle on GLOBAL source:
  // LDS slot s of row co holds global slot s ^ ((co>>1)&3))
  constexpr int lgR = (R == 64) ? 6 : 7;
  size_t sgb[INSTS];
#pragma unroll
  for (int i = 0; i < INSTS; ++i) {
    int f  = wid * (BUFROWS / NW) + i * 16 + (lane >> 2);  // flat row in group
    int cc = f >> lgR;                // chunk within group
    int r  = f & (R - 1);             // row within chunk
    int half = r >> (lgR - 1);        // 0 = hi, 1 = lo  (16N rows each)
    int co   = r & (16 * N - 1);
    int slot = (lane & 3) ^ ((co >> 1) & 3);
    sgb[i] = (size_t)half * CoKpad + (size_t)(co0 + co) * Kpad + slot * 8 + cc * 32;
  }

  auto stage = [&](int grp, int buf) {
#pragma unroll
    for (int i = 0; i < INSTS; ++i) {
      const __hip_bfloat16* gp = wsp + sgb[i] + grp * (GRP * 32);
      __hip_bfloat16* lp = &lds[buf * BUFELEM + (wid * (BUFROWS / NW) + i * 16) * 32];
      __builtin_amdgcn_global_load_lds(
          (const __attribute__((address_space(1))) void*)gp,
          (__attribute__((address_space(3))) void*)lp, 16, 0, 0);
    }
  };

  const int cpt = Cip >> 5;            // chunks per tap (power of 2)
  const int lgcpt = __builtin_ctz(cpt);
  const int NGRP = (9 * cpt) / GRP;

  // rolling per-tap A addressing
  const __hip_bfloat16* apc[M];
  bool avc[M];
  auto mkaddr = [&](int tap) {
    int ty = (tap * 11) >> 5;          // tap/3 for 0..8
    int tx = tap - ty * 3;
    int dy = (ty - 1) * dil, dx = (tx - 1) * dil;
#pragma unroll
    for (int m = 0; m < M; ++m) {
      int sy = y_[m] + dy, sx = x_[m] + dx;
      bool v = (sy >= 0) & (sy < H) & (sx >= 0) & (sx < W);
      avc[m] = v;
      int pix = v ? ((b_[m] << lgHW) + (sy << lgW) + sx) : 0;
      apc[m] = actin + (size_t)pix * Cip + 8 * g;
    }
  };

  const short8v zz = {};
  short8v aC[GRP][M], aN[GRP][M];

  auto prefA = [&](int grp, short8v (&dst)[GRP][M]) {
#pragma unroll
    for (int cc = 0; cc < GRP; ++cc) {
      int c = grp * GRP + cc;
      if ((c & (cpt - 1)) == 0) mkaddr(c >> lgcpt);   // wave-uniform
      int kc = (c & (cpt - 1)) << 5;
#pragma unroll
      for (int m = 0; m < M; ++m) {
        short8v t = *(const short8v*)(apc[m] + kc);
        dst[cc][m] = avc[m] ? t : zz;
      }
    }
  };

  f32x4 acc[M][N] = {};
  const int rdb = l15 * 32 + ((g ^ ((l15 >> 1) & 3)) * 8);  // swizzled read base

  // prologue: group 0
  stage(0, 0);
  prefA(0, aC);

  for (int gi = 0; gi < NGRP; ++gi) {
    __syncthreads();   // drains stage(gi)+prefA(gi) issued a full group ago

    if (gi + 1 < NGRP) {               // burst-issue next group's memory ops
      stage(gi + 1, (gi + 1) & 1);
      prefA(gi + 1, aN);
    }

    const __hip_bfloat16* bp = &lds[(gi & 1) * BUFELEM];
#pragma unroll
    for (int cc = 0; cc < GRP; ++cc) {
      short8v bh[N], bl[N];
#pragma unroll
      for (int j = 0; j < N; ++j) {
        bh[j] = *(const short8v*)(bp + cc * (R * 32) + j * 512 + rdb);
        bl[j] = *(const short8v*)(bp + cc * (R * 32) + (N * 512) + j * 512 + rdb);
      }
#pragma unroll
      for (int j = 0; j < N; ++j)
#pragma unroll
        for (int m = 0; m < M; ++m) {
          acc[m][j] = __builtin_amdgcn_mfma_f32_16x16x32_bf16(aC[cc][m], bh[j], acc[m][j], 0, 0, 0);
          acc[m][j] = __builtin_amdgcn_mfma_f32_16x16x32_bf16(aC[cc][m], bl[j], acc[m][j], 0, 0, 0);
        }
    }
#pragma unroll
    for (int cc = 0; cc < GRP; ++cc)
#pragma unroll
      for (int m = 0; m < M; ++m) aC[cc][m] = aN[cc][m];
  }

  // epilogue: BN + LIF.  D: co = co0 + j*16 + l15, pixel = p0 + m*16 + 4g + r
#pragma unroll
  for (int j = 0; j < N; ++j) {
    int c = co0 + j * 16 + l15;
    float ga = bnt[c], mu = bnt[Co + c], va = bnt[2 * Co + c];
    float sc = ga / sqrtf(va + BNEPS);
#pragma unroll
    for (int m = 0; m < M; ++m) {
      int pixb = p0 + m * 16 + 4 * g;
#pragma unroll
      for (int r = 0; r < 4; ++r) {
        size_t idx = (size_t)(pixb + r) * Co + c;
        float bno = (acc[m][j][r] - mu) * sc;
        float mv = LEAK * mem[idx] + bno;
        float s = (mv > THRS) ? 1.0f : 0.0f;
        actout[idx] = __float2bfloat16(s);
        mem[idx] = mv - s;
      }
    }
  }
}

// AvgPool(3,2,1) storing SUM (exact ints in bf16); /9 folded into next layer weights.
// channel-last, vectorized: one thread = 8 channels of one output pixel.
__global__ void avgpool_sum8(const __hip_bfloat16* __restrict__ in,
                             __hip_bfloat16* __restrict__ out, int C, int H, int W) {
  const int Ho = H >> 1, Wo = W >> 1;
  const int C8 = C >> 3;
  const int n = BB * Ho * Wo * C8;
  int i = blockIdx.x * 256 + threadIdx.x;
  if (i >= n) return;
  int c8 = i % C8; int t = i / C8;
  int xo = t % Wo; t /= Wo;
  int yo = t % Ho; int b = t / Ho;
  const int y0 = 2 * yo - 1, x0 = 2 * xo - 1;
  float s[8] = {0, 0, 0, 0, 0, 0, 0, 0};
#pragma unroll
  for (int dy = 0; dy < 3; ++dy) {
    int iy = y0 + dy;
    if (iy < 0 || iy >= H) continue;
#pragma unroll
    for (int dx = 0; dx < 3; ++dx) {
      int ix = x0 + dx;
      if (ix < 0 || ix >= W) continue;
      short8v v = *(const short8v*)(in + (((size_t)b * H + iy) * W + ix) * C + c8 * 8);
#pragma unroll
      for (int e = 0; e < 8; ++e) {
        __hip_bfloat16_raw raw; raw.x = (unsigned short)v[e];
        s[e] += __bfloat162float(__hip_bfloat16(raw));
      }
    }
  }
  short8v o;
#pragma unroll
  for (int e = 0; e < 8; ++e) {
    __hip_bfloat16_raw raw = __hip_bfloat16_raw(__float2bfloat16(s[e]));
    o[e] = (short)raw.x;
  }
  *(short8v*)(out + (size_t)i * 8) = o;
}

// 1x1 conv 1024->21 @32x32, f32, accumulate into d_out. One wave per (b,pix).
__global__ void out_conv(const __hip_bfloat16* __restrict__ act,  // [B*1024px][1024ch]
                         const float* __restrict__ W8, float* __restrict__ out) {
  int gw = (blockIdx.x * 256 + threadIdx.x) >> 6;  // b*1024 + pix
  int lane = threadIdx.x & 63;
  int b = gw >> 10, pix = gw & 1023;
  const __hip_bfloat16* ap = act + ((size_t)gw << 10);
  float acc[NCLS];
#pragma unroll
  for (int c = 0; c < NCLS; ++c) acc[c] = 0.0f;
  for (int j = 0; j < 16; ++j) {
    int ci = j * 64 + lane;
    float av = __bfloat162float(ap[ci]);
#pragma unroll
    for (int c = 0; c < NCLS; ++c) acc[c] = fmaf(av, W8[c * 1024 + ci], acc[c]);
  }
#pragma unroll
  for (int c = 0; c < NCLS; ++c) {
    float v = acc[c];
    for (int off = 32; off; off >>= 1) v += __shfl_xor(v, off, 64);
    if (lane == 0) out[((size_t)b * NCLS + c) * 1024 + pix] += v;
  }
}

extern "C" void kernel_launch(void* const* d_in, const int* in_sizes, int n_in,
                              void* d_out, int out_size, void* d_ws, size_t ws_size,
                              hipStream_t stream) {
  const float* x = (const float*)d_in[0];
  const float* u = (const float*)d_in[1];
  const float* Wc[9];
  for (int i = 0; i < 9; ++i) Wc[i] = (const float*)d_in[2 + i];
  const float* bn[8];
  for (int i = 0; i < 8; ++i) bn[i] = (const float*)d_in[11 + i];

  const int Ci_[8]  = {3, 64, 64, 128, 128, 256, 256, 256};
  const int Cip_[8] = {32, 64, 64, 128, 128, 256, 256, 256};
  const int Co_[8]  = {64, 64, 128, 128, 256, 256, 256, 1024};
  const int HH_[8]  = {128, 128, 64, 64, 32, 32, 32, 32};
  const float wsc_[8] = {1.f, 1.f, 1.f / 9.f, 1.f, 1.f / 9.f, 1.f, 1.f, 1.f};

  float* ws = (float*)d_ws;
  size_t off = 0;
  auto align8 = [](size_t v) { return (v + 7) & ~(size_t)7; };

  float* memp[8];
  for (int i = 0; i < 8; ++i) {
    memp[i] = ws + off;
    off += (size_t)BB * HH_[i] * HH_[i] * Co_[i];
  }
  __hip_bfloat16* spk = (__hip_bfloat16*)(ws + off);
  off += (size_t)BB * 16384 * 32 / 2;
  const size_t zero_floats = off;                       // mem + spk zeroed each call
  __hip_bfloat16* actA = (__hip_bfloat16*)(ws + off); off += 2097152;
  __hip_bfloat16* actB = (__hip_bfloat16*)(ws + off); off += 2097152;
  __hip_bfloat16* wall[8];
  for (int i = 0; i < 8; ++i) {
    size_t n = (size_t)Co_[i] * 9 * Cip_[i];            // per half
    wall[i] = (__hip_bfloat16*)(ws + off);
    off = align8(off + n);                              // hi + lo = n floats
  }

  zero_f32<<<2048, 256, 0, stream>>>(ws, (int)zero_floats);
  zero_f32<<<(BB * NCLS * 1024 + 255) / 256, 256, 0, stream>>>((float*)d_out, BB * NCLS * 1024);

  for (int i = 0; i < 8; ++i) {
    int n = Co_[i] * 9 * Cip_[i];
    wsplit<<<(n + 255) / 256, 256, 0, stream>>>(Wc[i], wall[i], wall[i] + n,
                                                Co_[i], Ci_[i], Cip_[i], wsc_[i]);
  }

  const size_t uT = (size_t)BB * 3 * 16384;
  for (int t = 0; t < TT; ++t) {
    spike_gen<<<(BB * 16384 + 255) / 256, 256, 0, stream>>>(x, u + (size_t)t * uT, spk);
    // L0: 3(32)->64 @128   tile 32x64, 512 blk, 2048 waves
    gemm_lif<2, 4, 3><<<512, 256, 0, stream>>>(spk,  wall[0], bn[0] + (size_t)t * 3 * 64,   memp[0], actA, 32,  64,   14, 7, 1, 9);
    // L1: 64->64 @128
    gemm_lif<2, 4, 3><<<512, 256, 0, stream>>>(actA, wall[1], bn[1] + (size_t)t * 3 * 64,   memp[1], actB, 64,  64,   14, 7, 1, 9);
    avgpool_sum8<<<(BB * 64 * 64 * 8 + 255) / 256, 256, 0, stream>>>(actB, actA, 64, 128, 128);
    // L2: 64->128 @64 (weights pre-scaled 1/9)   tile 32x32
    gemm_lif<2, 2, 3><<<512, 256, 0, stream>>>(actA, wall[2], bn[2] + (size_t)t * 3 * 128,  memp[2], actB, 64,  128,  12, 6, 1, 7);
    // L3: 128->128 @64
    gemm_lif<2, 2, 4><<<512, 256, 0, stream>>>(actB, wall[3], bn[3] + (size_t)t * 3 * 128,  memp[3], actA, 128, 128,  12, 6, 1, 7);
    avgpool_sum8<<<(BB * 32 * 32 * 16 + 255) / 256, 256, 0, stream>>>(actA, actB, 128, 64, 64);
    // L4: 128->256 @32 (weights pre-scaled 1/9)   tile 16x32
    gemm_lif<1, 2, 4><<<512, 64 * 4, 0, stream>>>(actB, wall[4], bn[4] + (size_t)t * 3 * 256,   memp[4], actA, 128, 256,  10, 5, 1, 6);
    // L5: 256->256 @32 dil2
    gemm_lif<1, 2, 8><<<512, 256, 0, stream>>>(actA, wall[5], bn[5] + (size_t)t * 3 * 256,   memp[5], actB, 256, 256,  10, 5, 2, 6);
    // L6: 256->256 @32 dil2
    gemm_lif<1, 2, 8><<<512, 256, 0, stream>>>(actB, wall[6], bn[6] + (size_t)t * 3 * 256,   memp[6], actA, 256, 256,  10, 5, 2, 6);
    // L7: 256->1024 @32 dil12   tile 32x64
    gemm_lif<2, 4, 4><<<512, 256, 0, stream>>>(actA, wall[7], bn[7] + (size_t)t * 3 * 1024, memp[7], actB, 256, 1024, 10, 5, 12, 5);
    // output layer accumulation
    out_conv<<<dim3(BB * 1024 / 4), 256, 0, stream>>>(actB, Wc[8], (float*)d_out);
  }
  scale_f32<<<(BB * NCLS * 1024 + 255) / 256, 256, 0, stream>>>((float*)d_out, BB * NCLS * 1024, 1.0f / TT);
}